// Round 13
// baseline (342.343 us; speedup 1.0000x reference)
//
#include <hip/hip_runtime.h>
#include <hip/hip_bf16.h>

#define SEQ   2048
#define DM    1024
#define NH    16
#define DH    64
#define MAXD  128

#define LOG2E 1.44269504f

typedef __attribute__((ext_vector_type(8))) short  short8;   // 8 bf16 = 4 VGPRs
typedef __attribute__((ext_vector_type(4))) short  short4v;  // 4 bf16 = 2 VGPRs
typedef __attribute__((ext_vector_type(4))) float  float4v;  // MFMA 16x16 accumulator

__device__ __forceinline__ short8 ld8(const void* p) {
    short8 v; __builtin_memcpy(&v, p, 16); return v;
}
__device__ __forceinline__ void st8(void* p, short8 v) {
    __builtin_memcpy(p, &v, 16);
}
__device__ __forceinline__ short bf16bits(float f) {
    __hip_bfloat16 b = __float2bfloat16(f);
    short s; __builtin_memcpy(&s, &b, 2); return s;
}
__device__ __forceinline__ float bits2f(short s) {
    unsigned u = (unsigned)(unsigned short)s << 16;
    return __builtin_bit_cast(float, u);
}
// pack two floats -> two bf16 (round-half-up; operands in [0,1])
__device__ __forceinline__ unsigned packbf2(float a, float b) {
    unsigned ua = (__builtin_bit_cast(unsigned, a) + 0x8000u) >> 16;
    unsigned ub = (__builtin_bit_cast(unsigned, b) + 0x8000u) & 0xffff0000u;
    return ua | ub;
}
// pack two floats -> two fp16
__device__ __forceinline__ unsigned packh2(float a, float b) {
    _Float16 ha = (_Float16)a, hb = (_Float16)b;
    unsigned short ua, ub;
    __builtin_memcpy(&ua, &ha, 2); __builtin_memcpy(&ub, &hb, 2);
    return (unsigned)ua | ((unsigned)ub << 16);
}
__device__ __forceinline__ float f16tof(short s) {
    _Float16 h; __builtin_memcpy(&h, &s, 2); return (float)h;
}
// raw v_exp_f32 (2^x) — bypasses OCML denorm fixup (flush-to-zero is fine here)
__device__ __forceinline__ float fexp2(float x) {
    float r; asm("v_exp_f32 %0, %1" : "=v"(r) : "v"(x)); return r;
}

// async global->LDS, 16 B per lane. lds = WAVE-UNIFORM base (HW adds lane*16).
__device__ __forceinline__ void async16(void* lds, const void* g) {
    __builtin_amdgcn_global_load_lds(
        (const __attribute__((address_space(1))) unsigned int*)g,
        (__attribute__((address_space(3))) unsigned int*)lds, 16, 0, 0);
}

// ---------------------------------------------------------------------------
// Fused prep: weight transposes (fp32->bf16) + x fp32->bf16 convert.
// ---------------------------------------------------------------------------
__global__ __launch_bounds__(256) void prep_kernel(
    const float* __restrict__ wq, const float* __restrict__ wo,
    const float* __restrict__ x,
    __hip_bfloat16* __restrict__ wqT, __hip_bfloat16* __restrict__ woT,
    __hip_bfloat16* __restrict__ xb) {
    const int t = threadIdx.x;
    const int bx = blockIdx.x;
    if (bx >= 128) {
        const size_t id = (size_t)(bx - 128) * 32 + blockIdx.y;
        const size_t i  = id * 2048 + t * 8;
        float f[8]; __builtin_memcpy(f, x + i, 32);
        short8 v;
#pragma unroll
        for (int j = 0; j < 8; ++j) v[j] = bf16bits(f[j]);
        st8(xb + i, v);
        return;
    }
    __shared__ __hip_bfloat16 tile[32][33];
    const int tx = t % 32, ty = t / 32;
    const int r0 = blockIdx.y * 32;
    const float* src; __hip_bfloat16* dst; int ss, ds, c0;
    if (bx < 96) { src = wq; dst = wqT; ss = 3 * DM; ds = DM; c0 = bx * 32; }
    else         { src = wo; dst = woT; ss = DM;     ds = DM; c0 = (bx - 96) * 32; }
#pragma unroll
    for (int i = 0; i < 4; ++i)
        tile[ty + i * 8][tx] = __float2bfloat16(src[(size_t)(r0 + ty + i * 8) * ss + c0 + tx]);
    __syncthreads();
#pragma unroll
    for (int i = 0; i < 4; ++i)
        dst[(size_t)(c0 + ty + i * 8) * ds + r0 + tx] = tile[tx][ty + i * 8];
}

// ---------------------------------------------------------------------------
// GEMM1 v2: 128x128 tile, BK=64, m97-structure with T2 XOR-swizzle.
// Pre-swizzled global source (rule 21) + XOR-swizzled ds_read. Grid 24x16.
// V-blocks (col0>=2048): transpose to vT via Tv aliased over As/Bs.
// ---------------------------------------------------------------------------
__global__ __launch_bounds__(256) void gemm_qkv(
    const __hip_bfloat16* __restrict__ A,
    const __hip_bfloat16* __restrict__ BT,
    __hip_bfloat16* __restrict__ C,
    __hip_bfloat16* __restrict__ vTg,
    int M, int N, int K) {
    __shared__ short Smem[2 * 128 * 64];         // As (16 KB) | Bs (16 KB)
    short* As = Smem;
    short* Bs = Smem + 128 * 64;

    const int t = threadIdx.x;
    const int w = t >> 6, lane = t & 63;
    const int l15 = lane & 15, quad = lane >> 4;
    const int row0 = blockIdx.y * 128;
    const int col0 = blockIdx.x * 128;
    const int wm = w >> 1, wn = w & 1;

    float4v acc[4][4];
#pragma unroll
    for (int i = 0; i < 4; ++i)
#pragma unroll
        for (int j = 0; j < 4; ++j) acc[i][j] = (float4v){0.f, 0.f, 0.f, 0.f};

    const int rowoff  = w * 8 + (lane >> 3);
    const int lanecol = (((lane & 7) ^ ((lane >> 3) & 7)) << 4);   // bytes
    const char* ap = (const char*)A  + ((size_t)(row0 + rowoff) * K) * 2 + lanecol;
    const char* bp = (const char*)BT + ((size_t)(col0 + rowoff) * K) * 2 + lanecol;

    const int swr = (l15 & 7) << 4;    // read-side XOR (row&7 == l15&7)

    for (int k0 = 0; k0 < K; k0 += 64) {
#pragma unroll
        for (int p = 0; p < 4; ++p)
            async16(&As[p * 2048 + w * 512], ap + (size_t)p * 32 * K * 2 + k0 * 2);
#pragma unroll
        for (int p = 0; p < 4; ++p)
            async16(&Bs[p * 2048 + w * 512], bp + (size_t)p * 32 * K * 2 + k0 * 2);
        __syncthreads();   // compiler emits vmcnt(0) drain: tile resident

#pragma unroll
        for (int kc = 0; kc < 2; ++kc) {
            short8 af[4], bf[4];
#pragma unroll
            for (int mt = 0; mt < 4; ++mt) {
                const int ra = wm * 64 + mt * 16 + l15;
                af[mt] = ld8((const char*)As + ra * 128 + ((kc * 64 + quad * 16) ^ swr));
            }
#pragma unroll
            for (int nt = 0; nt < 4; ++nt) {
                const int rb = wn * 64 + nt * 16 + l15;
                bf[nt] = ld8((const char*)Bs + rb * 128 + ((kc * 64 + quad * 16) ^ swr));
            }
#pragma unroll
            for (int mt = 0; mt < 4; ++mt)
#pragma unroll
                for (int nt = 0; nt < 4; ++nt)
                    acc[mt][nt] = __builtin_amdgcn_mfma_f32_16x16x32_bf16(
                        af[mt], bf[nt], acc[mt][nt], 0, 0, 0);
        }
        __syncthreads();
    }

    if (col0 < 2 * DM) {
#pragma unroll
        for (int mt = 0; mt < 4; ++mt)
#pragma unroll
            for (int nt = 0; nt < 4; ++nt)
#pragma unroll
                for (int r = 0; r < 4; ++r) {
                    const int row = row0 + wm * 64 + mt * 16 + quad * 4 + r;
                    const int col = col0 + wn * 64 + nt * 16 + l15;
                    C[(size_t)row * N + col] = __float2bfloat16(acc[mt][nt][r]);
                }
    } else {
        short* Tv = Smem;                 // 64 x 132 = 16.5 KB < 32 KB
#pragma unroll
        for (int H = 0; H < 2; ++H) {
            if (wn == H) {
#pragma unroll
                for (int mt = 0; mt < 4; ++mt)
#pragma unroll
                    for (int nt = 0; nt < 4; ++nt)
#pragma unroll
                        for (int r = 0; r < 4; ++r)
                            Tv[(nt * 16 + l15) * 132 + wm * 64 + mt * 16 + quad * 4 + r] =
                                bf16bits(acc[mt][nt][r]);
            }
            __syncthreads();
#pragma unroll
            for (int p = 0; p < 4; ++p) {
                const int idx = p * 256 + t;
                const int dl = idx >> 4, uu = idx & 15;
                st8(&vTg[((size_t)(col0 - 2 * DM) + H * 64 + dl) * SEQ + row0 + uu * 8],
                    ld8(&Tv[dl * 132 + uu * 8]));
            }
            __syncthreads();
        }
    }
}

// ---------------------------------------------------------------------------
// GEMM3 v2: 64x64 tiles, BK=64, T2 XOR-swizzle (as gemm_qkv v2). fp32 out.
// ---------------------------------------------------------------------------
__global__ __launch_bounds__(256) void gemm_out(
    const __hip_bfloat16* __restrict__ A,
    const __hip_bfloat16* __restrict__ BT,
    float* __restrict__ C,
    int M, int N, int K) {
    __shared__ short As[64 * 64];        // 8 KB, 128B rows (swz content)
    __shared__ short Bs[64 * 64];        // 8 KB

    const int t = threadIdx.x;
    const int w = t >> 6, lane = t & 63;
    const int l15 = lane & 15, quad = lane >> 4;
    const int row0 = blockIdx.y * 64;
    const int col0 = blockIdx.x * 64;
    const int wm = w >> 1, wn = w & 1;

    float4v acc[2][2];
#pragma unroll
    for (int i = 0; i < 2; ++i)
#pragma unroll
        for (int j = 0; j < 2; ++j) acc[i][j] = (float4v){0.f, 0.f, 0.f, 0.f};

    const int rowoff  = w * 8 + (lane >> 3);
    const int lanecol = (((lane & 7) ^ ((lane >> 3) & 7)) << 4);   // bytes
    const char* ap = (const char*)A  + ((size_t)(row0 + rowoff) * K) * 2 + lanecol;
    const char* bp = (const char*)BT + ((size_t)(col0 + rowoff) * K) * 2 + lanecol;

    const int swr = (l15 & 7) << 4;    // read-side XOR (row&7 == l15&7)

    for (int k0 = 0; k0 < K; k0 += 64) {
#pragma unroll
        for (int r = 0; r < 2; ++r)
            async16(&As[r * 2048 + w * 512], ap + (size_t)r * 32 * K * 2 + k0 * 2);
#pragma unroll
        for (int r = 0; r < 2; ++r)
            async16(&Bs[r * 2048 + w * 512], bp + (size_t)r * 32 * K * 2 + k0 * 2);
        __syncthreads();

#pragma unroll
        for (int kc = 0; kc < 2; ++kc) {
            short8 af[2], bf[2];
#pragma unroll
            for (int mt = 0; mt < 2; ++mt) {
                const int ra = wm * 32 + mt * 16 + l15;
                af[mt] = ld8((const char*)As + ra * 128 + ((kc * 64 + quad * 16) ^ swr));
            }
#pragma unroll
            for (int nt = 0; nt < 2; ++nt) {
                const int rb = wn * 32 + nt * 16 + l15;
                bf[nt] = ld8((const char*)Bs + rb * 128 + ((kc * 64 + quad * 16) ^ swr));
            }
#pragma unroll
            for (int mt = 0; mt < 2; ++mt)
#pragma unroll
                for (int nt = 0; nt < 2; ++nt)
                    acc[mt][nt] = __builtin_amdgcn_mfma_f32_16x16x32_bf16(
                        af[mt], bf[nt], acc[mt][nt], 0, 0, 0);
        }
        __syncthreads();
    }

#pragma unroll
    for (int mt = 0; mt < 2; ++mt)
#pragma unroll
        for (int nt = 0; nt < 2; ++nt)
#pragma unroll
            for (int r = 0; r < 4; ++r) {
                const int row = row0 + wm * 32 + mt * 16 + quad * 4 + r;
                const int col = col0 + wn * 32 + nt * 16 + l15;
                C[(size_t)row * N + col] = acc[mt][nt][r];
            }
}

// ---------------------------------------------------------------------------
// Flash attention v9: v8's in-register-P body at a SPILL-FREE occupancy point.
// Round-12 failure mode: __launch_bounds__(256,4) capped VGPR at 64 while the
// body needs ~150 (s_acc 64 + o_acc 32 + qf 16 + temps) -> 460 MB scratch
// traffic, 112 us. Fix: __launch_bounds__(256,3) -> 170-VGPR budget (fits),
// split-KV x3 (grid 768 = 3 blocks/CU; LDS 33.3 KB x3 = 100 KB, wide margin
// unlike round-7's 159.7 KB). 12 waves/CU vs the proven baseline's 8.
// In-register P: 16x16 C/D row layout (quad*4+r) == 16x16x16 B k-layout
// (quad*4+j), so S^T stripes feed v_mfma_f32_16x16x16_bf16 directly.
// grid decode (round-7-verified): xcd=id&7; qb=(id>>3)&15;
// c=(id&7)+8*(id>>7) in [0,48); h=c&15; part=c>>4; parts own {5,5,6} tiles.
// ---------------------------------------------------------------------------
#define TK    128            // keys per tile
#define NTT   (SEQ / TK)     // 16 tiles total
#define NPART 3

__global__ __launch_bounds__(256, 3) void attn_part(
    const __hip_bfloat16* __restrict__ qkv,
    const __hip_bfloat16* __restrict__ vT,
    const float* __restrict__ rel_bias,
    short* __restrict__ opart01,        // fp16 bits, parts 0,1: [2][SEQ][DM]
    short* __restrict__ opart2,         // fp16 bits, part 2: [SEQ][DM] (d_out scratch)
    float* __restrict__ ml) {           // [NPART][SEQ][NH][2] = (m, l)
    __shared__ short Kt[TK * 64];        // [key][d]   128B rows, swz content (16 KB)
    __shared__ short Vt[DH * TK];        // [d][key]   256B rows, swz content (16 KB)
    __shared__ float biasL[MAXD];

    const int t = threadIdx.x;
    const int w = t >> 6, lane = t & 63;
    const int l15 = lane & 15, quad = lane >> 4;

    const int id = blockIdx.x;           // XCD swizzle: id%8 = XCD (round-robin)
    const int qb = (id >> 3) & 15;
    const int c  = (id & 7) + 8 * (id >> 7);   // [0,48)
    const int h  = c & 15;
    const int part = c >> 4;                   // [0,3)
    const int kb_lo = (part * NTT) / NPART;        // 0,5,10
    const int kb_hi = ((part + 1) * NTT) / NPART;  // 5,10,16
    const int qw = qb * 128 + w * 32;    // wave's 32 q-rows: qw + qg*16 + l15

    if (t < MAXD) biasL[t] = rel_bias[t * NH + h] * LOG2E;

    // persistent Q fragments (B-operand: col=q=l15, k=d contiguous),
    // pre-scaled by 0.125*log2e (exp2 domain)
    short8 qf[2][2];
#pragma unroll
    for (int qg = 0; qg < 2; ++qg)
#pragma unroll
        for (int cc = 0; cc < 2; ++cc) {
            short8 raw = ld8(qkv + (size_t)(qw + qg * 16 + l15) * (3 * DM) + h * DH + cc * 32 + quad * 8);
#pragma unroll
            for (int j = 0; j < 8; ++j) qf[qg][cc][j] = bf16bits(bits2f(raw[j]) * (0.125f * LOG2E));
        }

    // staging base pointers, pre-swizzled for linear LDS dest (rule 21).
    const char* kpB; const char* vpB;
    {
        const char* kqb = (const char*)qkv + (size_t)(DM + h * DH) * 2;
        const char* vqb = (const char*)vT  + (size_t)(h * DH) * SEQ * 2;
        const int rK = w * 8 + (lane >> 3);
        const int cK = ((lane & 7) * 16) ^ ((rK & 7) << 4);
        kpB = kqb + (size_t)rK * (3 * DM * 2) + cK;
        const int rV = w * 4 + quad;
        const int cV = (l15 * 16) ^ ((rV & 7) << 4);
        vpB = vqb + (size_t)rV * (SEQ * 2) + cV;
    }

    float4v o_acc[4][2];                 // O^T: [nt (d-block)][qg]
#pragma unroll
    for (int nt = 0; nt < 4; ++nt)
#pragma unroll
        for (int qg = 0; qg < 2; ++qg) o_acc[nt][qg] = (float4v){0.f, 0.f, 0.f, 0.f};
    float m_i[2] = {-1e30f, -1e30f}, l_i[2] = {0.f, 0.f};

    const int swr = (l15 & 7) << 4;      // read-side XOR (row&7 == l15&7)

    for (int kb = kb_lo; kb < kb_hi; ++kb) {
        const int k0 = kb * TK;
        // stage K [key][d] and V [d][key] via DMA (swizzled source, linear dest)
        const char* ks = kpB + (size_t)k0 * (3 * DM * 2);
        const char* vs = vpB + (size_t)k0 * 2;
#pragma unroll
        for (int p = 0; p < 4; ++p)
            async16(&Kt[p * 2048 + w * 512], ks + (size_t)p * (32 * 3 * DM * 2));
#pragma unroll
        for (int p = 0; p < 4; ++p)
            async16(&Vt[p * 2048 + w * 512], vs + (size_t)p * (16 * SEQ * 2));
        __syncthreads();   // vmcnt(0) drain: tile resident (also publishes biasL)

        // S^T = mfma(K, Q): each kf read feeds both q-groups
        float4v s_acc[2][8];
#pragma unroll
        for (int qg = 0; qg < 2; ++qg)
#pragma unroll
            for (int kt = 0; kt < 8; ++kt) s_acc[qg][kt] = (float4v){0.f, 0.f, 0.f, 0.f};
#pragma unroll
        for (int cc = 0; cc < 2; ++cc)
#pragma unroll
            for (int kt = 0; kt < 8; ++kt) {
                short8 kf = ld8((const char*)Kt + (kt * 16 + l15) * 128 + ((cc * 64 + quad * 16) ^ swr));
                s_acc[0][kt] = __builtin_amdgcn_mfma_f32_16x16x32_bf16(kf, qf[0][cc], s_acc[0][kt], 0, 0, 0);
                s_acc[1][kt] = __builtin_amdgcn_mfma_f32_16x16x32_bf16(kf, qf[1][cc], s_acc[1][kt], 0, 0, 0);
            }

        // bias in-place (wave-uniform fast path at max distance)
        const int dlo = k0 - (qw + 31);
        const int dhi = qw - (k0 + TK - 1);
        if (dlo >= MAXD - 1 || dhi >= MAXD - 1) {
            const float bu = biasL[MAXD - 1];
#pragma unroll
            for (int qg = 0; qg < 2; ++qg)
#pragma unroll
                for (int kt = 0; kt < 8; ++kt)
#pragma unroll
                    for (int r = 0; r < 4; ++r) s_acc[qg][kt][r] += bu;
        } else {
#pragma unroll
            for (int qg = 0; qg < 2; ++qg) {
                const int qrow = qw + qg * 16 + l15;
#pragma unroll
                for (int kt = 0; kt < 8; ++kt)
#pragma unroll
                    for (int r = 0; r < 4; ++r) {
                        const int kg = k0 + kt * 16 + quad * 4 + r;
                        int rel = kg - qrow; if (rel < 0) rel = -rel;
                        if (rel > MAXD - 1) rel = MAXD - 1;
                        s_acc[qg][kt][r] += biasL[rel];
                    }
            }
        }

        // online softmax: per-lane q (= l15 + 16*qg); in-lane trees + 2 shfl
        float al[2];
#pragma unroll
        for (int qg = 0; qg < 2; ++qg) {
            float mk[8];
#pragma unroll
            for (int kt = 0; kt < 8; ++kt)
                mk[kt] = fmaxf(fmaxf(s_acc[qg][kt][0], s_acc[qg][kt][1]),
                               fmaxf(s_acc[qg][kt][2], s_acc[qg][kt][3]));
            float m = fmaxf(fmaxf(fmaxf(mk[0], mk[1]), fmaxf(mk[2], mk[3])),
                            fmaxf(fmaxf(mk[4], mk[5]), fmaxf(mk[6], mk[7])));
            m = fmaxf(m, __shfl_xor(m, 16, 64));
            m = fmaxf(m, __shfl_xor(m, 32, 64));
            const float mn = fmaxf(m_i[qg], m);
            al[qg] = fexp2(m_i[qg] - mn);
            m_i[qg] = mn;
            float sk[8];
#pragma unroll
            for (int kt = 0; kt < 8; ++kt) {
                float p0 = fexp2(s_acc[qg][kt][0] - mn);
                float p1 = fexp2(s_acc[qg][kt][1] - mn);
                float p2 = fexp2(s_acc[qg][kt][2] - mn);
                float p3 = fexp2(s_acc[qg][kt][3] - mn);
                s_acc[qg][kt][0] = p0; s_acc[qg][kt][1] = p1;
                s_acc[qg][kt][2] = p2; s_acc[qg][kt][3] = p3;
                sk[kt] = (p0 + p1) + (p2 + p3);
            }
            float rs = ((sk[0] + sk[1]) + (sk[2] + sk[3])) +
                       ((sk[4] + sk[5]) + (sk[6] + sk[7]));
            rs += __shfl_xor(rs, 16, 64);
            rs += __shfl_xor(rs, 32, 64);
            l_i[qg] = l_i[qg] * al[qg] + rs;
        }
#pragma unroll
        for (int nt = 0; nt < 4; ++nt)
#pragma unroll
            for (int qg = 0; qg < 2; ++qg)
#pragma unroll
                for (int r = 0; r < 4; ++r) o_acc[nt][qg][r] *= al[qg];

        // O^T += V·P via 16x16x16 MFMA: P stripes are ALREADY valid B-frags
        // (k=quad*4+j == C-row quad*4+r). No LDS P traffic, no barrier here.
#pragma unroll
        for (int kt = 0; kt < 8; ++kt) {
            unsigned a0 = packbf2(s_acc[0][kt][0], s_acc[0][kt][1]);
            unsigned a1 = packbf2(s_acc[0][kt][2], s_acc[0][kt][3]);
            short4v pb0 = __builtin_bit_cast(short4v,
                (unsigned long long)a0 | ((unsigned long long)a1 << 32));
            unsigned b0 = packbf2(s_acc[1][kt][0], s_acc[1][kt][1]);
            unsigned b1 = packbf2(s_acc[1][kt][2], s_acc[1][kt][3]);
            short4v pb1 = __builtin_bit_cast(short4v,
                (unsigned long long)b0 | ((unsigned long long)b1 << 32));
            const int voff = (kt * 32 + quad * 8) ^ swr;   // stays in 16B granule
#pragma unroll
            for (int nt = 0; nt < 4; ++nt) {
                short4v vf;   // V[d=16nt+l15][key=16kt+quad*4+..+3], b64 read
                __builtin_memcpy(&vf, (const char*)Vt + (nt * 16 + l15) * 256 + voff, 8);
                o_acc[nt][0] = __builtin_amdgcn_mfma_f32_16x16x16bf16_1k(vf, pb0, o_acc[nt][0], 0, 0, 0);
                o_acc[nt][1] = __builtin_amdgcn_mfma_f32_16x16x16bf16_1k(vf, pb1, o_acc[nt][1], 0, 0, 0);
            }
        }

        // all waves done reading Kt/Vt -> safe to overwrite next iteration
        __syncthreads();
    }

    // epilogue: normalized partial O (fp16, b64 stores) + (m, l) per q-row
    short* opb = (part < 2) ? (opart01 + (size_t)part * SEQ * DM) : opart2;
#pragma unroll
    for (int qg = 0; qg < 2; ++qg) {
        const float inv = 1.f / l_i[qg];
        const int qrow = qw + qg * 16 + l15;
#pragma unroll
        for (int nt = 0; nt < 4; ++nt) {
            unsigned d0 = packh2(o_acc[nt][qg][0] * inv, o_acc[nt][qg][1] * inv);
            unsigned d1 = packh2(o_acc[nt][qg][2] * inv, o_acc[nt][qg][3] * inv);
            unsigned long long v = (unsigned long long)d0 | ((unsigned long long)d1 << 32);
            __builtin_memcpy(opb + (size_t)qrow * DM + h * DH + nt * 16 + quad * 4, &v, 8);
        }
    }
    if (quad == 0) {
#pragma unroll
        for (int qg = 0; qg < 2; ++qg) {
            const int qrow = qw + qg * 16 + l15;
            float* mp = ml + (((size_t)part * SEQ + qrow) * NH + h) * 2;
            mp[0] = m_i[qg];
            mp[1] = l_i[qg];
        }
    }
}

// ---------------------------------------------------------------------------
// Combine the three KV-part partials: out = sum_i w_i * o_i,
// w_i = l_i * 2^(m_i - mx) / den. ~28 MB traffic. 1024 blocks x 256 thr.
// part 2 lives in d_out scratch (consumed here before gemm_out writes it).
// ---------------------------------------------------------------------------
__global__ __launch_bounds__(256) void combine_kernel(
    const short* __restrict__ opart01,   // fp16 bits, [2][SEQ][DM]
    const short* __restrict__ opart2,    // fp16 bits, [SEQ][DM] (d_out scratch)
    const float* __restrict__ ml,        // [NPART][SEQ][NH][2]
    __hip_bfloat16* __restrict__ attnb) {
    const size_t e = ((size_t)blockIdx.x * 256 + threadIdx.x) * 8;
    const int row = (int)(e >> 10);
    const int c0  = (int)(e & 1023);
    const int h   = c0 >> 6;

    const float* mp0 = ml + ((size_t)row * NH + h) * 2;
    const float* mp1 = mp0 + (size_t)SEQ * NH * 2;
    const float* mp2 = mp1 + (size_t)SEQ * NH * 2;
    const float m0 = mp0[0], l0 = mp0[1];
    const float m1 = mp1[0], l1 = mp1[1];
    const float m2 = mp2[0], l2 = mp2[1];
    const float mx = fmaxf(fmaxf(m0, m1), m2);
    const float e0 = fexp2(m0 - mx) * l0;
    const float e1 = fexp2(m1 - mx) * l1;
    const float e2 = fexp2(m2 - mx) * l2;
    const float inv = 1.f / (e0 + e1 + e2);
    const float w0 = e0 * inv, w1 = e1 * inv, w2 = e2 * inv;

    short8 a = ld8(opart01 + (size_t)row * DM + c0);
    short8 b = ld8(opart01 + (size_t)SEQ * DM + (size_t)row * DM + c0);
    short8 cc = ld8(opart2 + (size_t)row * DM + c0);
    short8 o;
#pragma unroll
    for (int j = 0; j < 8; ++j)
        o[j] = bf16bits(w0 * f16tof(a[j]) + w1 * f16tof(b[j]) + w2 * f16tof(cc[j]));
    st8(attnb + (size_t)row * DM + c0, o);
}

extern "C" void kernel_launch(void* const* d_in, const int* in_sizes, int n_in,
                              void* d_out, int out_size, void* d_ws, size_t ws_size,
                              hipStream_t stream) {
    const float* x        = (const float*)d_in[0];
    const float* w_qkv    = (const float*)d_in[1];
    const float* w_out    = (const float*)d_in[2];
    const float* rel_bias = (const float*)d_in[3];
    float* out = (float*)d_out;

    // ws layout (16-B aligned), 32 MiB total
    char* p = (char*)d_ws;
    __hip_bfloat16* xb    = (__hip_bfloat16*)p;  p += (size_t)SEQ * DM * 2;      // [0,4)   MiB
    __hip_bfloat16* wqT   = (__hip_bfloat16*)p;  p += (size_t)3 * DM * DM * 2;   // [4,10)  MiB
    __hip_bfloat16* woT   = (__hip_bfloat16*)p;  p += (size_t)DM * DM * 2;       // [10,12) MiB
    __hip_bfloat16* qkvb  = (__hip_bfloat16*)p;  p += (size_t)SEQ * 3 * DM * 2;  // [12,24) MiB
    __hip_bfloat16* vT    = (__hip_bfloat16*)p;  p += (size_t)DM * SEQ * 2;      // [24,28) MiB
    __hip_bfloat16* attnb = (__hip_bfloat16*)p;                                  // [28,32) MiB

    // split-KV x3 partial overlays:
    //   opart01 fp16 [2][SEQ][DM] = 8 MiB at ws[0,8)   (xb+wqT dead after gemm_qkv)
    //   ml fp32 [3][SEQ][NH][2]   = 0.75 MiB at ws[8,8.75) (inside dead wqT)
    //   opart2 fp16 [SEQ][DM]     = 4 MiB in d_out     (scratch until gemm_out;
    //       combine consumes it before gemm_out writes — stream-ordered)
    short* opart01 = (short*)d_ws;
    float* ml      = (float*)((char*)d_ws + ((size_t)8 << 20));
    short* opart2  = (short*)d_out;

    prep_kernel<<<dim3(160, 32), 256, 0, stream>>>(w_qkv, w_out, x, wqT, woT, xb);

    // 1) qkv = x @ w_qkv (128x128 swizzled tiles); V transposed to vT in-epilogue
    gemm_qkv<<<dim3(3 * DM / 128, SEQ / 128), 256, 0, stream>>>(
        xb, wqT, qkvb, vT, SEQ, 3 * DM, DM);

    // 2) attention: in-register-P split-KV x3 (768 blocks -> 3 blocks/CU,
    //    12 waves/CU, spill-free 170-VGPR budget), then 3-way combine
    attn_part<<<768, 256, 0, stream>>>(qkvb, vT, rel_bias, opart01, opart2, ml);
    combine_kernel<<<1024, 256, 0, stream>>>(opart01, opart2, ml, attnb);

    // 3) out = attn @ w_out
    gemm_out<<<dim3(DM / 64, SEQ / 64), 256, 0, stream>>>(
        attnb, woT, out, SEQ, DM, DM);
}

// Round 14
// 150.761 us; speedup vs baseline: 2.2708x; 2.2708x over previous
//
#include <hip/hip_runtime.h>
#include <hip/hip_bf16.h>

#define SEQ   2048
#define DM    1024
#define NH    16
#define DH    64
#define MAXD  128

#define LOG2E 1.44269504f

typedef __attribute__((ext_vector_type(8))) short  short8;   // 8 bf16 = 4 VGPRs
typedef __attribute__((ext_vector_type(4))) short  short4v;  // 4 bf16 = 2 VGPRs
typedef __attribute__((ext_vector_type(4))) float  float4v;  // MFMA 16x16 accumulator

__device__ __forceinline__ short8 ld8(const void* p) {
    short8 v; __builtin_memcpy(&v, p, 16); return v;
}
__device__ __forceinline__ void st8(void* p, short8 v) {
    __builtin_memcpy(p, &v, 16);
}
__device__ __forceinline__ short bf16bits(float f) {
    __hip_bfloat16 b = __float2bfloat16(f);
    short s; __builtin_memcpy(&s, &b, 2); return s;
}
__device__ __forceinline__ float bits2f(short s) {
    unsigned u = (unsigned)(unsigned short)s << 16;
    return __builtin_bit_cast(float, u);
}
// pack two floats -> two bf16 (round-half-up; operands in [0,1])
__device__ __forceinline__ unsigned packbf2(float a, float b) {
    unsigned ua = (__builtin_bit_cast(unsigned, a) + 0x8000u) >> 16;
    unsigned ub = (__builtin_bit_cast(unsigned, b) + 0x8000u) & 0xffff0000u;
    return ua | ub;
}
// pack two floats -> two fp16
__device__ __forceinline__ unsigned packh2(float a, float b) {
    _Float16 ha = (_Float16)a, hb = (_Float16)b;
    unsigned short ua, ub;
    __builtin_memcpy(&ua, &ha, 2); __builtin_memcpy(&ub, &hb, 2);
    return (unsigned)ua | ((unsigned)ub << 16);
}
__device__ __forceinline__ float f16tof(short s) {
    _Float16 h; __builtin_memcpy(&h, &s, 2); return (float)h;
}
// raw v_exp_f32 (2^x) — bypasses OCML denorm fixup (flush-to-zero is fine here)
__device__ __forceinline__ float fexp2(float x) {
    float r; asm("v_exp_f32 %0, %1" : "=v"(r) : "v"(x)); return r;
}

// async global->LDS, 16 B per lane. lds = WAVE-UNIFORM base (HW adds lane*16).
__device__ __forceinline__ void async16(void* lds, const void* g) {
    __builtin_amdgcn_global_load_lds(
        (const __attribute__((address_space(1))) unsigned int*)g,
        (__attribute__((address_space(3))) unsigned int*)lds, 16, 0, 0);
}

// ---------------------------------------------------------------------------
// Fused prep: weight transposes (fp32->bf16) + x fp32->bf16 convert.
// ---------------------------------------------------------------------------
__global__ __launch_bounds__(256) void prep_kernel(
    const float* __restrict__ wq, const float* __restrict__ wo,
    const float* __restrict__ x,
    __hip_bfloat16* __restrict__ wqT, __hip_bfloat16* __restrict__ woT,
    __hip_bfloat16* __restrict__ xb) {
    const int t = threadIdx.x;
    const int bx = blockIdx.x;
    if (bx >= 128) {
        const size_t id = (size_t)(bx - 128) * 32 + blockIdx.y;
        const size_t i  = id * 2048 + t * 8;
        float f[8]; __builtin_memcpy(f, x + i, 32);
        short8 v;
#pragma unroll
        for (int j = 0; j < 8; ++j) v[j] = bf16bits(f[j]);
        st8(xb + i, v);
        return;
    }
    __shared__ __hip_bfloat16 tile[32][33];
    const int tx = t % 32, ty = t / 32;
    const int r0 = blockIdx.y * 32;
    const float* src; __hip_bfloat16* dst; int ss, ds, c0;
    if (bx < 96) { src = wq; dst = wqT; ss = 3 * DM; ds = DM; c0 = bx * 32; }
    else         { src = wo; dst = woT; ss = DM;     ds = DM; c0 = (bx - 96) * 32; }
#pragma unroll
    for (int i = 0; i < 4; ++i)
        tile[ty + i * 8][tx] = __float2bfloat16(src[(size_t)(r0 + ty + i * 8) * ss + c0 + tx]);
    __syncthreads();
#pragma unroll
    for (int i = 0; i < 4; ++i)
        dst[(size_t)(c0 + ty + i * 8) * ds + r0 + tx] = tile[tx][ty + i * 8];
}

// ---------------------------------------------------------------------------
// GEMM1 v2: 128x128 tile, BK=64, m97-structure with T2 XOR-swizzle.
// Pre-swizzled global source (rule 21) + XOR-swizzled ds_read. Grid 24x16.
// V-blocks (col0>=2048): transpose to vT via Tv aliased over As/Bs.
// ---------------------------------------------------------------------------
__global__ __launch_bounds__(256) void gemm_qkv(
    const __hip_bfloat16* __restrict__ A,
    const __hip_bfloat16* __restrict__ BT,
    __hip_bfloat16* __restrict__ C,
    __hip_bfloat16* __restrict__ vTg,
    int M, int N, int K) {
    __shared__ short Smem[2 * 128 * 64];         // As (16 KB) | Bs (16 KB)
    short* As = Smem;
    short* Bs = Smem + 128 * 64;

    const int t = threadIdx.x;
    const int w = t >> 6, lane = t & 63;
    const int l15 = lane & 15, quad = lane >> 4;
    const int row0 = blockIdx.y * 128;
    const int col0 = blockIdx.x * 128;
    const int wm = w >> 1, wn = w & 1;

    float4v acc[4][4];
#pragma unroll
    for (int i = 0; i < 4; ++i)
#pragma unroll
        for (int j = 0; j < 4; ++j) acc[i][j] = (float4v){0.f, 0.f, 0.f, 0.f};

    const int rowoff  = w * 8 + (lane >> 3);
    const int lanecol = (((lane & 7) ^ ((lane >> 3) & 7)) << 4);   // bytes
    const char* ap = (const char*)A  + ((size_t)(row0 + rowoff) * K) * 2 + lanecol;
    const char* bp = (const char*)BT + ((size_t)(col0 + rowoff) * K) * 2 + lanecol;

    const int swr = (l15 & 7) << 4;    // read-side XOR (row&7 == l15&7)

    for (int k0 = 0; k0 < K; k0 += 64) {
#pragma unroll
        for (int p = 0; p < 4; ++p)
            async16(&As[p * 2048 + w * 512], ap + (size_t)p * 32 * K * 2 + k0 * 2);
#pragma unroll
        for (int p = 0; p < 4; ++p)
            async16(&Bs[p * 2048 + w * 512], bp + (size_t)p * 32 * K * 2 + k0 * 2);
        __syncthreads();   // compiler emits vmcnt(0) drain: tile resident

#pragma unroll
        for (int kc = 0; kc < 2; ++kc) {
            short8 af[4], bf[4];
#pragma unroll
            for (int mt = 0; mt < 4; ++mt) {
                const int ra = wm * 64 + mt * 16 + l15;
                af[mt] = ld8((const char*)As + ra * 128 + ((kc * 64 + quad * 16) ^ swr));
            }
#pragma unroll
            for (int nt = 0; nt < 4; ++nt) {
                const int rb = wn * 64 + nt * 16 + l15;
                bf[nt] = ld8((const char*)Bs + rb * 128 + ((kc * 64 + quad * 16) ^ swr));
            }
#pragma unroll
            for (int mt = 0; mt < 4; ++mt)
#pragma unroll
                for (int nt = 0; nt < 4; ++nt)
                    acc[mt][nt] = __builtin_amdgcn_mfma_f32_16x16x32_bf16(
                        af[mt], bf[nt], acc[mt][nt], 0, 0, 0);
        }
        __syncthreads();
    }

    if (col0 < 2 * DM) {
#pragma unroll
        for (int mt = 0; mt < 4; ++mt)
#pragma unroll
            for (int nt = 0; nt < 4; ++nt)
#pragma unroll
                for (int r = 0; r < 4; ++r) {
                    const int row = row0 + wm * 64 + mt * 16 + quad * 4 + r;
                    const int col = col0 + wn * 64 + nt * 16 + l15;
                    C[(size_t)row * N + col] = __float2bfloat16(acc[mt][nt][r]);
                }
    } else {
        short* Tv = Smem;                 // 64 x 132 = 16.5 KB < 32 KB
#pragma unroll
        for (int H = 0; H < 2; ++H) {
            if (wn == H) {
#pragma unroll
                for (int mt = 0; mt < 4; ++mt)
#pragma unroll
                    for (int nt = 0; nt < 4; ++nt)
#pragma unroll
                        for (int r = 0; r < 4; ++r)
                            Tv[(nt * 16 + l15) * 132 + wm * 64 + mt * 16 + quad * 4 + r] =
                                bf16bits(acc[mt][nt][r]);
            }
            __syncthreads();
#pragma unroll
            for (int p = 0; p < 4; ++p) {
                const int idx = p * 256 + t;
                const int dl = idx >> 4, uu = idx & 15;
                st8(&vTg[((size_t)(col0 - 2 * DM) + H * 64 + dl) * SEQ + row0 + uu * 8],
                    ld8(&Tv[dl * 132 + uu * 8]));
            }
            __syncthreads();
        }
    }
}

// ---------------------------------------------------------------------------
// GEMM3 v2: 64x64 tiles, BK=64, T2 XOR-swizzle (as gemm_qkv v2). fp32 out.
// ---------------------------------------------------------------------------
__global__ __launch_bounds__(256) void gemm_out(
    const __hip_bfloat16* __restrict__ A,
    const __hip_bfloat16* __restrict__ BT,
    float* __restrict__ C,
    int M, int N, int K) {
    __shared__ short As[64 * 64];        // 8 KB, 128B rows (swz content)
    __shared__ short Bs[64 * 64];        // 8 KB

    const int t = threadIdx.x;
    const int w = t >> 6, lane = t & 63;
    const int l15 = lane & 15, quad = lane >> 4;
    const int row0 = blockIdx.y * 64;
    const int col0 = blockIdx.x * 64;
    const int wm = w >> 1, wn = w & 1;

    float4v acc[2][2];
#pragma unroll
    for (int i = 0; i < 2; ++i)
#pragma unroll
        for (int j = 0; j < 2; ++j) acc[i][j] = (float4v){0.f, 0.f, 0.f, 0.f};

    const int rowoff  = w * 8 + (lane >> 3);
    const int lanecol = (((lane & 7) ^ ((lane >> 3) & 7)) << 4);   // bytes
    const char* ap = (const char*)A  + ((size_t)(row0 + rowoff) * K) * 2 + lanecol;
    const char* bp = (const char*)BT + ((size_t)(col0 + rowoff) * K) * 2 + lanecol;

    const int swr = (l15 & 7) << 4;    // read-side XOR (row&7 == l15&7)

    for (int k0 = 0; k0 < K; k0 += 64) {
#pragma unroll
        for (int r = 0; r < 2; ++r)
            async16(&As[r * 2048 + w * 512], ap + (size_t)r * 32 * K * 2 + k0 * 2);
#pragma unroll
        for (int r = 0; r < 2; ++r)
            async16(&Bs[r * 2048 + w * 512], bp + (size_t)r * 32 * K * 2 + k0 * 2);
        __syncthreads();

#pragma unroll
        for (int kc = 0; kc < 2; ++kc) {
            short8 af[2], bf[2];
#pragma unroll
            for (int mt = 0; mt < 2; ++mt) {
                const int ra = wm * 32 + mt * 16 + l15;
                af[mt] = ld8((const char*)As + ra * 128 + ((kc * 64 + quad * 16) ^ swr));
            }
#pragma unroll
            for (int nt = 0; nt < 2; ++nt) {
                const int rb = wn * 32 + nt * 16 + l15;
                bf[nt] = ld8((const char*)Bs + rb * 128 + ((kc * 64 + quad * 16) ^ swr));
            }
#pragma unroll
            for (int mt = 0; mt < 2; ++mt)
#pragma unroll
                for (int nt = 0; nt < 2; ++nt)
                    acc[mt][nt] = __builtin_amdgcn_mfma_f32_16x16x32_bf16(
                        af[mt], bf[nt], acc[mt][nt], 0, 0, 0);
        }
        __syncthreads();
    }

#pragma unroll
    for (int mt = 0; mt < 2; ++mt)
#pragma unroll
        for (int nt = 0; nt < 2; ++nt)
#pragma unroll
            for (int r = 0; r < 4; ++r) {
                const int row = row0 + wm * 32 + mt * 16 + quad * 4 + r;
                const int col = col0 + wn * 32 + nt * 16 + l15;
                C[(size_t)row * N + col] = acc[mt][nt][r];
            }
}

// ---------------------------------------------------------------------------
// Flash attention v10: in-register-P body (correctness HW-verified in rounds
// 12/13) at the UNCAPPED proven occupancy point. Rounds 12/13 failure mode
// was the __launch_bounds__ VGPR cap (64 / 84 VGPR -> 400+ MB scratch spill);
// here __launch_bounds__(256,2) gives the 256-VGPR budget where round-5-style
// bodies allocated cleanly (120 VGPR). Config = round-10 v7 (the 152.2 us
// best): split-KV x2, grid 512, 2 blocks/CU, async16 swizzled K/V staging.
// Change vs v7: PV uses v_mfma_f32_16x16x16_bf16 with P stripes direct from
// s_acc (C/D row quad*4+r == B k-layout quad*4+j) -> P LDS region deleted
// (69->33 KB), its write/read traffic and VALU gone; 2 barriers/tile kept.
// grid decode: xcd=id&7; qb=(id>>3)&15; c=(id&7)+8*(id>>7) in [0,32);
// h=c&15; half=c>>4.
// ---------------------------------------------------------------------------
#define TK    128            // keys per tile
#define NTILE (SEQ / 2 / TK) // 8 tiles per half

__global__ __launch_bounds__(256, 2) void attn_part(
    const __hip_bfloat16* __restrict__ qkv,
    const __hip_bfloat16* __restrict__ vT,
    const float* __restrict__ rel_bias,
    short* __restrict__ opart,          // fp16 bits, [half][SEQ][DM]
    float* __restrict__ ml) {           // [half][SEQ][NH][2] = (m, l)
    __shared__ short Kt[TK * 64];        // [key][d]   128B rows, swz content (16 KB)
    __shared__ short Vt[DH * TK];        // [d][key]   256B rows, swz content (16 KB)
    __shared__ float biasL[MAXD];

    const int t = threadIdx.x;
    const int w = t >> 6, lane = t & 63;
    const int l15 = lane & 15, quad = lane >> 4;

    const int id = blockIdx.x;           // XCD swizzle: id%8 = XCD (round-robin)
    const int qb = (id >> 3) & 15;
    const int c  = (id & 7) + 8 * (id >> 7);   // [0,32)
    const int h  = c & 15;
    const int half = c >> 4;
    const int kbase = half * (SEQ / 2);
    const int qw = qb * 128 + w * 32;    // wave's 32 q-rows: qw + qg*16 + l15

    if (t < MAXD) biasL[t] = rel_bias[t * NH + h] * LOG2E;

    // persistent Q fragments (B-operand: col=q=l15, k=d contiguous),
    // pre-scaled by 0.125*log2e (exp2 domain)
    short8 qf[2][2];
#pragma unroll
    for (int qg = 0; qg < 2; ++qg)
#pragma unroll
        for (int cc = 0; cc < 2; ++cc) {
            short8 raw = ld8(qkv + (size_t)(qw + qg * 16 + l15) * (3 * DM) + h * DH + cc * 32 + quad * 8);
#pragma unroll
            for (int j = 0; j < 8; ++j) qf[qg][cc][j] = bf16bits(bits2f(raw[j]) * (0.125f * LOG2E));
        }

    // staging base pointers, pre-swizzled for linear LDS dest (rule 21).
    const char* kpB; const char* vpB;
    {
        const char* kqb = (const char*)qkv + (size_t)(DM + h * DH) * 2;
        const char* vqb = (const char*)vT  + (size_t)(h * DH) * SEQ * 2;
        const int rK = w * 8 + (lane >> 3);
        const int cK = ((lane & 7) * 16) ^ ((rK & 7) << 4);
        kpB = kqb + (size_t)rK * (3 * DM * 2) + cK;
        const int rV = w * 4 + quad;
        const int cV = (l15 * 16) ^ ((rV & 7) << 4);
        vpB = vqb + (size_t)rV * (SEQ * 2) + cV;
    }

    float4v o_acc[4][2];                 // O^T: [nt (d-block)][qg]
#pragma unroll
    for (int nt = 0; nt < 4; ++nt)
#pragma unroll
        for (int qg = 0; qg < 2; ++qg) o_acc[nt][qg] = (float4v){0.f, 0.f, 0.f, 0.f};
    float m_i[2] = {-1e30f, -1e30f}, l_i[2] = {0.f, 0.f};

    const int swr = (l15 & 7) << 4;      // read-side XOR (row&7 == l15&7)

    for (int kb = 0; kb < NTILE; ++kb) {
        const int k0 = kbase + kb * TK;
        // stage K [key][d] and V [d][key] via DMA (swizzled source, linear dest)
        const char* ks = kpB + (size_t)k0 * (3 * DM * 2);
        const char* vs = vpB + (size_t)k0 * 2;
#pragma unroll
        for (int p = 0; p < 4; ++p)
            async16(&Kt[p * 2048 + w * 512], ks + (size_t)p * (32 * 3 * DM * 2));
#pragma unroll
        for (int p = 0; p < 4; ++p)
            async16(&Vt[p * 2048 + w * 512], vs + (size_t)p * (16 * SEQ * 2));
        __syncthreads();   // vmcnt(0) drain: tile resident (also publishes biasL)

        // S^T = mfma(K, Q): each kf read feeds both q-groups
        float4v s_acc[2][8];
#pragma unroll
        for (int qg = 0; qg < 2; ++qg)
#pragma unroll
            for (int kt = 0; kt < 8; ++kt) s_acc[qg][kt] = (float4v){0.f, 0.f, 0.f, 0.f};
#pragma unroll
        for (int cc = 0; cc < 2; ++cc)
#pragma unroll
            for (int kt = 0; kt < 8; ++kt) {
                short8 kf = ld8((const char*)Kt + (kt * 16 + l15) * 128 + ((cc * 64 + quad * 16) ^ swr));
                s_acc[0][kt] = __builtin_amdgcn_mfma_f32_16x16x32_bf16(kf, qf[0][cc], s_acc[0][kt], 0, 0, 0);
                s_acc[1][kt] = __builtin_amdgcn_mfma_f32_16x16x32_bf16(kf, qf[1][cc], s_acc[1][kt], 0, 0, 0);
            }

        // bias in-place (wave-uniform fast path at max distance)
        const int dlo = k0 - (qw + 31);
        const int dhi = qw - (k0 + TK - 1);
        if (dlo >= MAXD - 1 || dhi >= MAXD - 1) {
            const float bu = biasL[MAXD - 1];
#pragma unroll
            for (int qg = 0; qg < 2; ++qg)
#pragma unroll
                for (int kt = 0; kt < 8; ++kt)
#pragma unroll
                    for (int r = 0; r < 4; ++r) s_acc[qg][kt][r] += bu;
        } else {
#pragma unroll
            for (int qg = 0; qg < 2; ++qg) {
                const int qrow = qw + qg * 16 + l15;
#pragma unroll
                for (int kt = 0; kt < 8; ++kt)
#pragma unroll
                    for (int r = 0; r < 4; ++r) {
                        const int kg = k0 + kt * 16 + quad * 4 + r;
                        int rel = kg - qrow; if (rel < 0) rel = -rel;
                        if (rel > MAXD - 1) rel = MAXD - 1;
                        s_acc[qg][kt][r] += biasL[rel];
                    }
            }
        }

        // online softmax: per-lane q (= l15 + 16*qg); in-lane trees + 2 shfl
        float al[2];
#pragma unroll
        for (int qg = 0; qg < 2; ++qg) {
            float mk[8];
#pragma unroll
            for (int kt = 0; kt < 8; ++kt)
                mk[kt] = fmaxf(fmaxf(s_acc[qg][kt][0], s_acc[qg][kt][1]),
                               fmaxf(s_acc[qg][kt][2], s_acc[qg][kt][3]));
            float m = fmaxf(fmaxf(fmaxf(mk[0], mk[1]), fmaxf(mk[2], mk[3])),
                            fmaxf(fmaxf(mk[4], mk[5]), fmaxf(mk[6], mk[7])));
            m = fmaxf(m, __shfl_xor(m, 16, 64));
            m = fmaxf(m, __shfl_xor(m, 32, 64));
            const float mn = fmaxf(m_i[qg], m);
            al[qg] = fexp2(m_i[qg] - mn);
            m_i[qg] = mn;
            float sk[8];
#pragma unroll
            for (int kt = 0; kt < 8; ++kt) {
                float p0 = fexp2(s_acc[qg][kt][0] - mn);
                float p1 = fexp2(s_acc[qg][kt][1] - mn);
                float p2 = fexp2(s_acc[qg][kt][2] - mn);
                float p3 = fexp2(s_acc[qg][kt][3] - mn);
                s_acc[qg][kt][0] = p0; s_acc[qg][kt][1] = p1;
                s_acc[qg][kt][2] = p2; s_acc[qg][kt][3] = p3;
                sk[kt] = (p0 + p1) + (p2 + p3);
            }
            float rs = ((sk[0] + sk[1]) + (sk[2] + sk[3])) +
                       ((sk[4] + sk[5]) + (sk[6] + sk[7]));
            rs += __shfl_xor(rs, 16, 64);
            rs += __shfl_xor(rs, 32, 64);
            l_i[qg] = l_i[qg] * al[qg] + rs;
        }
#pragma unroll
        for (int nt = 0; nt < 4; ++nt)
#pragma unroll
            for (int qg = 0; qg < 2; ++qg)
#pragma unroll
                for (int r = 0; r < 4; ++r) o_acc[nt][qg][r] *= al[qg];

        // O^T += V·P via 16x16x16 MFMA: P stripes are ALREADY valid B-frags
        // (k=quad*4+j == C-row quad*4+r). No LDS P traffic, no extra barrier.
#pragma unroll
        for (int kt = 0; kt < 8; ++kt) {
            unsigned a0 = packbf2(s_acc[0][kt][0], s_acc[0][kt][1]);
            unsigned a1 = packbf2(s_acc[0][kt][2], s_acc[0][kt][3]);
            short4v pb0 = __builtin_bit_cast(short4v,
                (unsigned long long)a0 | ((unsigned long long)a1 << 32));
            unsigned b0 = packbf2(s_acc[1][kt][0], s_acc[1][kt][1]);
            unsigned b1 = packbf2(s_acc[1][kt][2], s_acc[1][kt][3]);
            short4v pb1 = __builtin_bit_cast(short4v,
                (unsigned long long)b0 | ((unsigned long long)b1 << 32));
            const int voff = (kt * 32 + quad * 8) ^ swr;   // stays in 16B granule
#pragma unroll
            for (int nt = 0; nt < 4; ++nt) {
                short4v vf;   // V[d=16nt+l15][key=16kt+quad*4+..+3], b64 read
                __builtin_memcpy(&vf, (const char*)Vt + (nt * 16 + l15) * 256 + voff, 8);
                o_acc[nt][0] = __builtin_amdgcn_mfma_f32_16x16x16bf16_1k(vf, pb0, o_acc[nt][0], 0, 0, 0);
                o_acc[nt][1] = __builtin_amdgcn_mfma_f32_16x16x16bf16_1k(vf, pb1, o_acc[nt][1], 0, 0, 0);
            }
        }

        // all waves done reading Kt/Vt -> safe to overwrite next iteration
        __syncthreads();
    }

    // epilogue: normalized partial O (fp16, b64 stores) + (m, l) per q-row
#pragma unroll
    for (int qg = 0; qg < 2; ++qg) {
        const float inv = 1.f / l_i[qg];
        const int qrow = qw + qg * 16 + l15;
#pragma unroll
        for (int nt = 0; nt < 4; ++nt) {
            unsigned d0 = packh2(o_acc[nt][qg][0] * inv, o_acc[nt][qg][1] * inv);
            unsigned d1 = packh2(o_acc[nt][qg][2] * inv, o_acc[nt][qg][3] * inv);
            unsigned long long v = (unsigned long long)d0 | ((unsigned long long)d1 << 32);
            __builtin_memcpy(opart + ((size_t)half * SEQ + qrow) * DM + h * DH + nt * 16 + quad * 4, &v, 8);
        }
    }
    if (quad == 0) {
#pragma unroll
        for (int qg = 0; qg < 2; ++qg) {
            const int qrow = qw + qg * 16 + l15;
            float* mp = ml + (((size_t)half * SEQ + qrow) * NH + h) * 2;
            mp[0] = m_i[qg];
            mp[1] = l_i[qg];
        }
    }
}

// ---------------------------------------------------------------------------
// Combine the two KV-half partials: out = w1*o1 + w2*o2,
// wi = li * 2^(mi - m) / sum. Memory-bound (~20 MB). 1024 blocks x 256 thr.
// ---------------------------------------------------------------------------
__global__ __launch_bounds__(256) void combine_kernel(
    const short* __restrict__ opart,     // fp16 bits, [half][SEQ][DM]
    const float* __restrict__ ml,        // [half][SEQ][NH][2]
    __hip_bfloat16* __restrict__ attnb) {
    const size_t e = ((size_t)blockIdx.x * 256 + threadIdx.x) * 8;
    const int row = (int)(e >> 10);
    const int c0  = (int)(e & 1023);
    const int h   = c0 >> 6;

    const float* mp1 = ml + ((size_t)row * NH + h) * 2;
    const float* mp2 = mp1 + (size_t)SEQ * NH * 2;
    const float m1 = mp1[0], l1 = mp1[1];
    const float m2 = mp2[0], l2 = mp2[1];
    const float mx = fmaxf(m1, m2);
    const float e1 = fexp2(m1 - mx) * l1;
    const float e2 = fexp2(m2 - mx) * l2;
    const float inv = 1.f / (e1 + e2);
    const float w1 = e1 * inv, w2 = e2 * inv;

    short8 a = ld8(opart + (size_t)row * DM + c0);
    short8 b = ld8(opart + (size_t)SEQ * DM + (size_t)row * DM + c0);
    short8 o;
#pragma unroll
    for (int j = 0; j < 8; ++j)
        o[j] = bf16bits(w1 * f16tof(a[j]) + w2 * f16tof(b[j]));
    st8(attnb + (size_t)row * DM + c0, o);
}

extern "C" void kernel_launch(void* const* d_in, const int* in_sizes, int n_in,
                              void* d_out, int out_size, void* d_ws, size_t ws_size,
                              hipStream_t stream) {
    const float* x        = (const float*)d_in[0];
    const float* w_qkv    = (const float*)d_in[1];
    const float* w_out    = (const float*)d_in[2];
    const float* rel_bias = (const float*)d_in[3];
    float* out = (float*)d_out;

    // ws layout (16-B aligned), 32 MiB total
    char* p = (char*)d_ws;
    __hip_bfloat16* xb    = (__hip_bfloat16*)p;  p += (size_t)SEQ * DM * 2;      // [0,4)   MiB
    __hip_bfloat16* wqT   = (__hip_bfloat16*)p;  p += (size_t)3 * DM * DM * 2;   // [4,10)  MiB
    __hip_bfloat16* woT   = (__hip_bfloat16*)p;  p += (size_t)DM * DM * 2;       // [10,12) MiB
    __hip_bfloat16* qkvb  = (__hip_bfloat16*)p;  p += (size_t)SEQ * 3 * DM * 2;  // [12,24) MiB
    __hip_bfloat16* vT    = (__hip_bfloat16*)p;  p += (size_t)DM * SEQ * 2;      // [24,28) MiB
    __hip_bfloat16* attnb = (__hip_bfloat16*)p;                                  // [28,32) MiB

    // split-KV partials overlay the xb+wqT region ([0,10MiB)), dead after
    // gemm_qkv: opart fp16 [2][SEQ][DM] = 8 MiB, ml fp32 [2][SEQ][NH][2] = 0.5 MiB
    short* opart = (short*)d_ws;
    float* ml    = (float*)((char*)d_ws + (size_t)2 * SEQ * DM * 2);

    prep_kernel<<<dim3(160, 32), 256, 0, stream>>>(w_qkv, w_out, x, wqT, woT, xb);

    // 1) qkv = x @ w_qkv (128x128 swizzled tiles); V transposed to vT in-epilogue
    gemm_qkv<<<dim3(3 * DM / 128, SEQ / 128), 256, 0, stream>>>(
        xb, wqT, qkvb, vT, SEQ, 3 * DM, DM);

    // 2) attention: in-register-P split-KV x2 (uncapped VGPR budget), combine
    attn_part<<<512, 256, 0, stream>>>(qkvb, vT, rel_bias, opart, ml);
    combine_kernel<<<1024, 256, 0, stream>>>(opart, ml, attnb);

    // 3) out = attn @ w_out
    gemm_out<<<dim3(DM / 64, SEQ / 64), 256, 0, stream>>>(
        attnb, woT, out, SEQ, DM, DM);
}

// Round 15
// 146.464 us; speedup vs baseline: 2.3374x; 1.0293x over previous
//
#include <hip/hip_runtime.h>
#include <hip/hip_bf16.h>

#define SEQ   2048
#define DM    1024
#define NH    16
#define DH    64
#define MAXD  128

#define LOG2E 1.44269504f

typedef __attribute__((ext_vector_type(8))) short  short8;   // 8 bf16 = 4 VGPRs
typedef __attribute__((ext_vector_type(4))) short  short4v;  // 4 bf16 = 2 VGPRs
typedef __attribute__((ext_vector_type(4))) float  float4v;  // MFMA 16x16 accumulator

__device__ __forceinline__ short8 ld8(const void* p) {
    short8 v; __builtin_memcpy(&v, p, 16); return v;
}
__device__ __forceinline__ void st8(void* p, short8 v) {
    __builtin_memcpy(p, &v, 16);
}
__device__ __forceinline__ short bf16bits(float f) {
    __hip_bfloat16 b = __float2bfloat16(f);
    short s; __builtin_memcpy(&s, &b, 2); return s;
}
__device__ __forceinline__ float bits2f(short s) {
    unsigned u = (unsigned)(unsigned short)s << 16;
    return __builtin_bit_cast(float, u);
}
// pack two floats -> two bf16 (round-half-up; operands in [0,1])
__device__ __forceinline__ unsigned packbf2(float a, float b) {
    unsigned ua = (__builtin_bit_cast(unsigned, a) + 0x8000u) >> 16;
    unsigned ub = (__builtin_bit_cast(unsigned, b) + 0x8000u) & 0xffff0000u;
    return ua | ub;
}
// pack two floats -> two fp16
__device__ __forceinline__ unsigned packh2(float a, float b) {
    _Float16 ha = (_Float16)a, hb = (_Float16)b;
    unsigned short ua, ub;
    __builtin_memcpy(&ua, &ha, 2); __builtin_memcpy(&ub, &hb, 2);
    return (unsigned)ua | ((unsigned)ub << 16);
}
__device__ __forceinline__ float f16tof(short s) {
    _Float16 h; __builtin_memcpy(&h, &s, 2); return (float)h;
}
// raw v_exp_f32 (2^x) — bypasses OCML denorm fixup (flush-to-zero is fine here)
__device__ __forceinline__ float fexp2(float x) {
    float r; asm("v_exp_f32 %0, %1" : "=v"(r) : "v"(x)); return r;
}

// async global->LDS, 16 B per lane. lds = WAVE-UNIFORM base (HW adds lane*16).
__device__ __forceinline__ void async16(void* lds, const void* g) {
    __builtin_amdgcn_global_load_lds(
        (const __attribute__((address_space(1))) unsigned int*)g,
        (__attribute__((address_space(3))) unsigned int*)lds, 16, 0, 0);
}

// ---------------------------------------------------------------------------
// Fused prep: weight transposes (fp32->bf16) + x fp32->bf16 convert.
// ---------------------------------------------------------------------------
__global__ __launch_bounds__(256) void prep_kernel(
    const float* __restrict__ wq, const float* __restrict__ wo,
    const float* __restrict__ x,
    __hip_bfloat16* __restrict__ wqT, __hip_bfloat16* __restrict__ woT,
    __hip_bfloat16* __restrict__ xb) {
    const int t = threadIdx.x;
    const int bx = blockIdx.x;
    if (bx >= 128) {
        const size_t id = (size_t)(bx - 128) * 32 + blockIdx.y;
        const size_t i  = id * 2048 + t * 8;
        float f[8]; __builtin_memcpy(f, x + i, 32);
        short8 v;
#pragma unroll
        for (int j = 0; j < 8; ++j) v[j] = bf16bits(f[j]);
        st8(xb + i, v);
        return;
    }
    __shared__ __hip_bfloat16 tile[32][33];
    const int tx = t % 32, ty = t / 32;
    const int r0 = blockIdx.y * 32;
    const float* src; __hip_bfloat16* dst; int ss, ds, c0;
    if (bx < 96) { src = wq; dst = wqT; ss = 3 * DM; ds = DM; c0 = bx * 32; }
    else         { src = wo; dst = woT; ss = DM;     ds = DM; c0 = (bx - 96) * 32; }
#pragma unroll
    for (int i = 0; i < 4; ++i)
        tile[ty + i * 8][tx] = __float2bfloat16(src[(size_t)(r0 + ty + i * 8) * ss + c0 + tx]);
    __syncthreads();
#pragma unroll
    for (int i = 0; i < 4; ++i)
        dst[(size_t)(c0 + ty + i * 8) * ds + r0 + tx] = tile[tx][ty + i * 8];
}

// ---------------------------------------------------------------------------
// GEMM1 v3: 128x64 tile, BK=64, swizzled async16 staging (rule 21). Grid
// 48x16 = 768 blocks = 3 blocks/CU — fixes the v2 grid-occupancy limiter
// (384 blocks = 1.5/CU; round-4/5 A/B showed occupancy gain ~= conflict cost,
// so swizzle + 768 blocks captures both terms). Per K-step: 6 async16,
// 12 ds_read_b128 (conflict-free), 16 MFMA, 2 barriers.
// V-blocks (col0>=2048): single-pass transpose via Tv aliased over As|Bs.
// ---------------------------------------------------------------------------
__global__ __launch_bounds__(256) void gemm_qkv(
    const __hip_bfloat16* __restrict__ A,
    const __hip_bfloat16* __restrict__ BT,
    __hip_bfloat16* __restrict__ C,
    __hip_bfloat16* __restrict__ vTg,
    int M, int N, int K) {
    __shared__ short Smem[128 * 64 + 64 * 64];   // As 16 KB | Bs 8 KB
    short* As = Smem;
    short* Bs = Smem + 128 * 64;

    const int t = threadIdx.x;
    const int w = t >> 6, lane = t & 63;
    const int l15 = lane & 15, quad = lane >> 4;
    const int row0 = blockIdx.y * 128;
    const int col0 = blockIdx.x * 64;
    const int wm = w >> 1, wn = w & 1;

    float4v acc[4][2];
#pragma unroll
    for (int i = 0; i < 4; ++i)
#pragma unroll
        for (int j = 0; j < 2; ++j) acc[i][j] = (float4v){0.f, 0.f, 0.f, 0.f};

    // staging geometry: round covers 32 rows of 128B; row&7 == (lane>>3)&7
    const int rowoff  = w * 8 + (lane >> 3);
    const int lanecol = (((lane & 7) ^ ((lane >> 3) & 7)) << 4);   // bytes
    const char* ap = (const char*)A  + ((size_t)(row0 + rowoff) * K) * 2 + lanecol;
    const char* bp = (const char*)BT + ((size_t)(col0 + rowoff) * K) * 2 + lanecol;

    const int swr = (l15 & 7) << 4;    // read-side XOR (row&7 == l15&7)

    for (int k0 = 0; k0 < K; k0 += 64) {
#pragma unroll
        for (int p = 0; p < 4; ++p)
            async16(&As[p * 2048 + w * 512], ap + (size_t)p * 32 * K * 2 + k0 * 2);
#pragma unroll
        for (int r = 0; r < 2; ++r)
            async16(&Bs[r * 2048 + w * 512], bp + (size_t)r * 32 * K * 2 + k0 * 2);
        __syncthreads();   // compiler emits vmcnt(0) drain: tile resident

#pragma unroll
        for (int kc = 0; kc < 2; ++kc) {
            short8 af[4], bf[2];
#pragma unroll
            for (int mt = 0; mt < 4; ++mt) {
                const int ra = wm * 64 + mt * 16 + l15;
                af[mt] = ld8((const char*)As + ra * 128 + ((kc * 64 + quad * 16) ^ swr));
            }
#pragma unroll
            for (int nt = 0; nt < 2; ++nt) {
                const int rb = wn * 32 + nt * 16 + l15;
                bf[nt] = ld8((const char*)Bs + rb * 128 + ((kc * 64 + quad * 16) ^ swr));
            }
#pragma unroll
            for (int mt = 0; mt < 4; ++mt)
#pragma unroll
                for (int nt = 0; nt < 2; ++nt)
                    acc[mt][nt] = __builtin_amdgcn_mfma_f32_16x16x32_bf16(
                        af[mt], bf[nt], acc[mt][nt], 0, 0, 0);
        }
        __syncthreads();
    }

    if (col0 < 2 * DM) {
        // Q/K columns: plain C write
#pragma unroll
        for (int mt = 0; mt < 4; ++mt)
#pragma unroll
            for (int nt = 0; nt < 2; ++nt)
#pragma unroll
                for (int r = 0; r < 4; ++r) {
                    const int row = row0 + wm * 64 + mt * 16 + quad * 4 + r;
                    const int col = col0 + wn * 32 + nt * 16 + l15;
                    C[(size_t)row * N + col] = __float2bfloat16(acc[mt][nt][r]);
                }
    } else {
        // V columns: transpose to vT via Tv (64 x 132 = 16.9 KB < 24 KB Smem)
        short* Tv = Smem;
#pragma unroll
        for (int mt = 0; mt < 4; ++mt)
#pragma unroll
            for (int nt = 0; nt < 2; ++nt)
#pragma unroll
                for (int r = 0; r < 4; ++r)
                    Tv[(wn * 32 + nt * 16 + l15) * 132 + wm * 64 + mt * 16 + quad * 4 + r] =
                        bf16bits(acc[mt][nt][r]);
        __syncthreads();
#pragma unroll
        for (int p = 0; p < 4; ++p) {
            const int idx = p * 256 + t;
            const int dl = idx >> 4, uu = idx & 15;
            st8(&vTg[((size_t)(col0 - 2 * DM) + dl) * SEQ + row0 + uu * 8],
                ld8(&Tv[dl * 132 + uu * 8]));
        }
    }
}

// ---------------------------------------------------------------------------
// GEMM3 v2: 64x64 tiles, BK=64, T2 XOR-swizzle (as gemm_qkv). fp32 out.
// ---------------------------------------------------------------------------
__global__ __launch_bounds__(256) void gemm_out(
    const __hip_bfloat16* __restrict__ A,
    const __hip_bfloat16* __restrict__ BT,
    float* __restrict__ C,
    int M, int N, int K) {
    __shared__ short As[64 * 64];        // 8 KB, 128B rows (swz content)
    __shared__ short Bs[64 * 64];        // 8 KB

    const int t = threadIdx.x;
    const int w = t >> 6, lane = t & 63;
    const int l15 = lane & 15, quad = lane >> 4;
    const int row0 = blockIdx.y * 64;
    const int col0 = blockIdx.x * 64;
    const int wm = w >> 1, wn = w & 1;

    float4v acc[2][2];
#pragma unroll
    for (int i = 0; i < 2; ++i)
#pragma unroll
        for (int j = 0; j < 2; ++j) acc[i][j] = (float4v){0.f, 0.f, 0.f, 0.f};

    const int rowoff  = w * 8 + (lane >> 3);
    const int lanecol = (((lane & 7) ^ ((lane >> 3) & 7)) << 4);   // bytes
    const char* ap = (const char*)A  + ((size_t)(row0 + rowoff) * K) * 2 + lanecol;
    const char* bp = (const char*)BT + ((size_t)(col0 + rowoff) * K) * 2 + lanecol;

    const int swr = (l15 & 7) << 4;    // read-side XOR (row&7 == l15&7)

    for (int k0 = 0; k0 < K; k0 += 64) {
#pragma unroll
        for (int r = 0; r < 2; ++r)
            async16(&As[r * 2048 + w * 512], ap + (size_t)r * 32 * K * 2 + k0 * 2);
#pragma unroll
        for (int r = 0; r < 2; ++r)
            async16(&Bs[r * 2048 + w * 512], bp + (size_t)r * 32 * K * 2 + k0 * 2);
        __syncthreads();

#pragma unroll
        for (int kc = 0; kc < 2; ++kc) {
            short8 af[2], bf[2];
#pragma unroll
            for (int mt = 0; mt < 2; ++mt) {
                const int ra = wm * 32 + mt * 16 + l15;
                af[mt] = ld8((const char*)As + ra * 128 + ((kc * 64 + quad * 16) ^ swr));
            }
#pragma unroll
            for (int nt = 0; nt < 2; ++nt) {
                const int rb = wn * 32 + nt * 16 + l15;
                bf[nt] = ld8((const char*)Bs + rb * 128 + ((kc * 64 + quad * 16) ^ swr));
            }
#pragma unroll
            for (int mt = 0; mt < 2; ++mt)
#pragma unroll
                for (int nt = 0; nt < 2; ++nt)
                    acc[mt][nt] = __builtin_amdgcn_mfma_f32_16x16x32_bf16(
                        af[mt], bf[nt], acc[mt][nt], 0, 0, 0);
        }
        __syncthreads();
    }

#pragma unroll
    for (int mt = 0; mt < 2; ++mt)
#pragma unroll
        for (int nt = 0; nt < 2; ++nt)
#pragma unroll
            for (int r = 0; r < 4; ++r) {
                const int row = row0 + wm * 32 + mt * 16 + quad * 4 + r;
                const int col = col0 + wn * 32 + nt * 16 + l15;
                C[(size_t)row * N + col] = acc[mt][nt][r];
            }
}

// ---------------------------------------------------------------------------
// Flash attention v10 (UNCHANGED from the 150.8 us round-14 best):
// in-register P (C/D row quad*4+r == 16x16x16 B k-layout quad*4+j) at the
// uncapped __launch_bounds__(256,2) occupancy point; split-KV x2, async16
// swizzled K/V staging, 2 barriers/tile, LDS 33 KB.
// grid decode: xcd=id&7; qb=(id>>3)&15; c=(id&7)+8*(id>>7) in [0,32);
// h=c&15; half=c>>4.
// ---------------------------------------------------------------------------
#define TK    128            // keys per tile
#define NTILE (SEQ / 2 / TK) // 8 tiles per half

__global__ __launch_bounds__(256, 2) void attn_part(
    const __hip_bfloat16* __restrict__ qkv,
    const __hip_bfloat16* __restrict__ vT,
    const float* __restrict__ rel_bias,
    short* __restrict__ opart,          // fp16 bits, [half][SEQ][DM]
    float* __restrict__ ml) {           // [half][SEQ][NH][2] = (m, l)
    __shared__ short Kt[TK * 64];        // [key][d]   128B rows, swz content (16 KB)
    __shared__ short Vt[DH * TK];        // [d][key]   256B rows, swz content (16 KB)
    __shared__ float biasL[MAXD];

    const int t = threadIdx.x;
    const int w = t >> 6, lane = t & 63;
    const int l15 = lane & 15, quad = lane >> 4;

    const int id = blockIdx.x;           // XCD swizzle: id%8 = XCD (round-robin)
    const int qb = (id >> 3) & 15;
    const int c  = (id & 7) + 8 * (id >> 7);   // [0,32)
    const int h  = c & 15;
    const int half = c >> 4;
    const int kbase = half * (SEQ / 2);
    const int qw = qb * 128 + w * 32;    // wave's 32 q-rows: qw + qg*16 + l15

    if (t < MAXD) biasL[t] = rel_bias[t * NH + h] * LOG2E;

    // persistent Q fragments (B-operand: col=q=l15, k=d contiguous),
    // pre-scaled by 0.125*log2e (exp2 domain)
    short8 qf[2][2];
#pragma unroll
    for (int qg = 0; qg < 2; ++qg)
#pragma unroll
        for (int cc = 0; cc < 2; ++cc) {
            short8 raw = ld8(qkv + (size_t)(qw + qg * 16 + l15) * (3 * DM) + h * DH + cc * 32 + quad * 8);
#pragma unroll
            for (int j = 0; j < 8; ++j) qf[qg][cc][j] = bf16bits(bits2f(raw[j]) * (0.125f * LOG2E));
        }

    // staging base pointers, pre-swizzled for linear LDS dest (rule 21).
    const char* kpB; const char* vpB;
    {
        const char* kqb = (const char*)qkv + (size_t)(DM + h * DH) * 2;
        const char* vqb = (const char*)vT  + (size_t)(h * DH) * SEQ * 2;
        const int rK = w * 8 + (lane >> 3);
        const int cK = ((lane & 7) * 16) ^ ((rK & 7) << 4);
        kpB = kqb + (size_t)rK * (3 * DM * 2) + cK;
        const int rV = w * 4 + quad;
        const int cV = (l15 * 16) ^ ((rV & 7) << 4);
        vpB = vqb + (size_t)rV * (SEQ * 2) + cV;
    }

    float4v o_acc[4][2];                 // O^T: [nt (d-block)][qg]
#pragma unroll
    for (int nt = 0; nt < 4; ++nt)
#pragma unroll
        for (int qg = 0; qg < 2; ++qg) o_acc[nt][qg] = (float4v){0.f, 0.f, 0.f, 0.f};
    float m_i[2] = {-1e30f, -1e30f}, l_i[2] = {0.f, 0.f};

    const int swr = (l15 & 7) << 4;      // read-side XOR (row&7 == l15&7)

    for (int kb = 0; kb < NTILE; ++kb) {
        const int k0 = kbase + kb * TK;
        // stage K [key][d] and V [d][key] via DMA (swizzled source, linear dest)
        const char* ks = kpB + (size_t)k0 * (3 * DM * 2);
        const char* vs = vpB + (size_t)k0 * 2;
#pragma unroll
        for (int p = 0; p < 4; ++p)
            async16(&Kt[p * 2048 + w * 512], ks + (size_t)p * (32 * 3 * DM * 2));
#pragma unroll
        for (int p = 0; p < 4; ++p)
            async16(&Vt[p * 2048 + w * 512], vs + (size_t)p * (16 * SEQ * 2));
        __syncthreads();   // vmcnt(0) drain: tile resident (also publishes biasL)

        // S^T = mfma(K, Q): each kf read feeds both q-groups
        float4v s_acc[2][8];
#pragma unroll
        for (int qg = 0; qg < 2; ++qg)
#pragma unroll
            for (int kt = 0; kt < 8; ++kt) s_acc[qg][kt] = (float4v){0.f, 0.f, 0.f, 0.f};
#pragma unroll
        for (int cc = 0; cc < 2; ++cc)
#pragma unroll
            for (int kt = 0; kt < 8; ++kt) {
                short8 kf = ld8((const char*)Kt + (kt * 16 + l15) * 128 + ((cc * 64 + quad * 16) ^ swr));
                s_acc[0][kt] = __builtin_amdgcn_mfma_f32_16x16x32_bf16(kf, qf[0][cc], s_acc[0][kt], 0, 0, 0);
                s_acc[1][kt] = __builtin_amdgcn_mfma_f32_16x16x32_bf16(kf, qf[1][cc], s_acc[1][kt], 0, 0, 0);
            }

        // bias in-place (wave-uniform fast path at max distance)
        const int dlo = k0 - (qw + 31);
        const int dhi = qw - (k0 + TK - 1);
        if (dlo >= MAXD - 1 || dhi >= MAXD - 1) {
            const float bu = biasL[MAXD - 1];
#pragma unroll
            for (int qg = 0; qg < 2; ++qg)
#pragma unroll
                for (int kt = 0; kt < 8; ++kt)
#pragma unroll
                    for (int r = 0; r < 4; ++r) s_acc[qg][kt][r] += bu;
        } else {
#pragma unroll
            for (int qg = 0; qg < 2; ++qg) {
                const int qrow = qw + qg * 16 + l15;
#pragma unroll
                for (int kt = 0; kt < 8; ++kt)
#pragma unroll
                    for (int r = 0; r < 4; ++r) {
                        const int kg = k0 + kt * 16 + quad * 4 + r;
                        int rel = kg - qrow; if (rel < 0) rel = -rel;
                        if (rel > MAXD - 1) rel = MAXD - 1;
                        s_acc[qg][kt][r] += biasL[rel];
                    }
            }
        }

        // online softmax: per-lane q (= l15 + 16*qg); in-lane trees + 2 shfl
        float al[2];
#pragma unroll
        for (int qg = 0; qg < 2; ++qg) {
            float mk[8];
#pragma unroll
            for (int kt = 0; kt < 8; ++kt)
                mk[kt] = fmaxf(fmaxf(s_acc[qg][kt][0], s_acc[qg][kt][1]),
                               fmaxf(s_acc[qg][kt][2], s_acc[qg][kt][3]));
            float m = fmaxf(fmaxf(fmaxf(mk[0], mk[1]), fmaxf(mk[2], mk[3])),
                            fmaxf(fmaxf(mk[4], mk[5]), fmaxf(mk[6], mk[7])));
            m = fmaxf(m, __shfl_xor(m, 16, 64));
            m = fmaxf(m, __shfl_xor(m, 32, 64));
            const float mn = fmaxf(m_i[qg], m);
            al[qg] = fexp2(m_i[qg] - mn);
            m_i[qg] = mn;
            float sk[8];
#pragma unroll
            for (int kt = 0; kt < 8; ++kt) {
                float p0 = fexp2(s_acc[qg][kt][0] - mn);
                float p1 = fexp2(s_acc[qg][kt][1] - mn);
                float p2 = fexp2(s_acc[qg][kt][2] - mn);
                float p3 = fexp2(s_acc[qg][kt][3] - mn);
                s_acc[qg][kt][0] = p0; s_acc[qg][kt][1] = p1;
                s_acc[qg][kt][2] = p2; s_acc[qg][kt][3] = p3;
                sk[kt] = (p0 + p1) + (p2 + p3);
            }
            float rs = ((sk[0] + sk[1]) + (sk[2] + sk[3])) +
                       ((sk[4] + sk[5]) + (sk[6] + sk[7]));
            rs += __shfl_xor(rs, 16, 64);
            rs += __shfl_xor(rs, 32, 64);
            l_i[qg] = l_i[qg] * al[qg] + rs;
        }
#pragma unroll
        for (int nt = 0; nt < 4; ++nt)
#pragma unroll
            for (int qg = 0; qg < 2; ++qg)
#pragma unroll
                for (int r = 0; r < 4; ++r) o_acc[nt][qg][r] *= al[qg];

        // O^T += V·P via 16x16x16 MFMA: P stripes are ALREADY valid B-frags
        // (k=quad*4+j == C-row quad*4+r). No LDS P traffic, no extra barrier.
#pragma unroll
        for (int kt = 0; kt < 8; ++kt) {
            unsigned a0 = packbf2(s_acc[0][kt][0], s_acc[0][kt][1]);
            unsigned a1 = packbf2(s_acc[0][kt][2], s_acc[0][kt][3]);
            short4v pb0 = __builtin_bit_cast(short4v,
                (unsigned long long)a0 | ((unsigned long long)a1 << 32));
            unsigned b0 = packbf2(s_acc[1][kt][0], s_acc[1][kt][1]);
            unsigned b1 = packbf2(s_acc[1][kt][2], s_acc[1][kt][3]);
            short4v pb1 = __builtin_bit_cast(short4v,
                (unsigned long long)b0 | ((unsigned long long)b1 << 32));
            const int voff = (kt * 32 + quad * 8) ^ swr;   // stays in 16B granule
#pragma unroll
            for (int nt = 0; nt < 4; ++nt) {
                short4v vf;   // V[d=16nt+l15][key=16kt+quad*4+..+3], b64 read
                __builtin_memcpy(&vf, (const char*)Vt + (nt * 16 + l15) * 256 + voff, 8);
                o_acc[nt][0] = __builtin_amdgcn_mfma_f32_16x16x16bf16_1k(vf, pb0, o_acc[nt][0], 0, 0, 0);
                o_acc[nt][1] = __builtin_amdgcn_mfma_f32_16x16x16bf16_1k(vf, pb1, o_acc[nt][1], 0, 0, 0);
            }
        }

        // all waves done reading Kt/Vt -> safe to overwrite next iteration
        __syncthreads();
    }

    // epilogue: normalized partial O (fp16, b64 stores) + (m, l) per q-row
#pragma unroll
    for (int qg = 0; qg < 2; ++qg) {
        const float inv = 1.f / l_i[qg];
        const int qrow = qw + qg * 16 + l15;
#pragma unroll
        for (int nt = 0; nt < 4; ++nt) {
            unsigned d0 = packh2(o_acc[nt][qg][0] * inv, o_acc[nt][qg][1] * inv);
            unsigned d1 = packh2(o_acc[nt][qg][2] * inv, o_acc[nt][qg][3] * inv);
            unsigned long long v = (unsigned long long)d0 | ((unsigned long long)d1 << 32);
            __builtin_memcpy(opart + ((size_t)half * SEQ + qrow) * DM + h * DH + nt * 16 + quad * 4, &v, 8);
        }
    }
    if (quad == 0) {
#pragma unroll
        for (int qg = 0; qg < 2; ++qg) {
            const int qrow = qw + qg * 16 + l15;
            float* mp = ml + (((size_t)half * SEQ + qrow) * NH + h) * 2;
            mp[0] = m_i[qg];
            mp[1] = l_i[qg];
        }
    }
}

// ---------------------------------------------------------------------------
// Combine the two KV-half partials: out = w1*o1 + w2*o2,
// wi = li * 2^(mi - m) / sum. Memory-bound (~20 MB). 1024 blocks x 256 thr.
// ---------------------------------------------------------------------------
__global__ __launch_bounds__(256) void combine_kernel(
    const short* __restrict__ opart,     // fp16 bits, [half][SEQ][DM]
    const float* __restrict__ ml,        // [half][SEQ][NH][2]
    __hip_bfloat16* __restrict__ attnb) {
    const size_t e = ((size_t)blockIdx.x * 256 + threadIdx.x) * 8;
    const int row = (int)(e >> 10);
    const int c0  = (int)(e & 1023);
    const int h   = c0 >> 6;

    const float* mp1 = ml + ((size_t)row * NH + h) * 2;
    const float* mp2 = mp1 + (size_t)SEQ * NH * 2;
    const float m1 = mp1[0], l1 = mp1[1];
    const float m2 = mp2[0], l2 = mp2[1];
    const float mx = fmaxf(m1, m2);
    const float e1 = fexp2(m1 - mx) * l1;
    const float e2 = fexp2(m2 - mx) * l2;
    const float inv = 1.f / (e1 + e2);
    const float w1 = e1 * inv, w2 = e2 * inv;

    short8 a = ld8(opart + (size_t)row * DM + c0);
    short8 b = ld8(opart + (size_t)SEQ * DM + (size_t)row * DM + c0);
    short8 o;
#pragma unroll
    for (int j = 0; j < 8; ++j)
        o[j] = bf16bits(w1 * f16tof(a[j]) + w2 * f16tof(b[j]));
    st8(attnb + (size_t)row * DM + c0, o);
}

extern "C" void kernel_launch(void* const* d_in, const int* in_sizes, int n_in,
                              void* d_out, int out_size, void* d_ws, size_t ws_size,
                              hipStream_t stream) {
    const float* x        = (const float*)d_in[0];
    const float* w_qkv    = (const float*)d_in[1];
    const float* w_out    = (const float*)d_in[2];
    const float* rel_bias = (const float*)d_in[3];
    float* out = (float*)d_out;

    // ws layout (16-B aligned), 32 MiB total
    char* p = (char*)d_ws;
    __hip_bfloat16* xb    = (__hip_bfloat16*)p;  p += (size_t)SEQ * DM * 2;      // [0,4)   MiB
    __hip_bfloat16* wqT   = (__hip_bfloat16*)p;  p += (size_t)3 * DM * DM * 2;   // [4,10)  MiB
    __hip_bfloat16* woT   = (__hip_bfloat16*)p;  p += (size_t)DM * DM * 2;       // [10,12) MiB
    __hip_bfloat16* qkvb  = (__hip_bfloat16*)p;  p += (size_t)SEQ * 3 * DM * 2;  // [12,24) MiB
    __hip_bfloat16* vT    = (__hip_bfloat16*)p;  p += (size_t)DM * SEQ * 2;      // [24,28) MiB
    __hip_bfloat16* attnb = (__hip_bfloat16*)p;                                  // [28,32) MiB

    // split-KV partials overlay the xb+wqT region ([0,10MiB)), dead after
    // gemm_qkv: opart fp16 [2][SEQ][DM] = 8 MiB, ml fp32 [2][SEQ][NH][2] = 0.5 MiB
    short* opart = (short*)d_ws;
    float* ml    = (float*)((char*)d_ws + (size_t)2 * SEQ * DM * 2);

    prep_kernel<<<dim3(160, 32), 256, 0, stream>>>(w_qkv, w_out, x, wqT, woT, xb);

    // 1) qkv = x @ w_qkv (128x64 swizzled tiles, 768 blocks = 3/CU);
    //    V transposed to vT in-epilogue
    gemm_qkv<<<dim3(3 * DM / 64, SEQ / 128), 256, 0, stream>>>(
        xb, wqT, qkvb, vT, SEQ, 3 * DM, DM);

    // 2) attention: in-register-P split-KV x2 (uncapped VGPR budget), combine
    attn_part<<<512, 256, 0, stream>>>(qkvb, vT, rel_bias, opart, ml);
    combine_kernel<<<1024, 256, 0, stream>>>(opart, ml, attnb);

    // 3) out = attn @ w_out
    gemm_out<<<dim3(DM / 64, SEQ / 64), 256, 0, stream>>>(
        attnb, woT, out, SEQ, DM, DM);
}